// Round 13
// baseline (77.953 us; speedup 1.0000x reference)
//
#include <hip/hip_runtime.h>
#include <hip/hip_fp16.h>

#define OUT_H 7
#define OUT_W 7
#define NPOS  49
#define RATIO 2
#define SCALE 0.25f
#define CCH 256
#define FH 200
#define FW 200
#define FHW (FH * FW)          // 40000
#define PIXB (CCH * 2)         // 512 B per pixel row in featT
#define DEPTH 3                // staging ring slots per wave

// ---------------- Transpose: (B, 256, 40000) fp32 -> (B, 40000, 256) fp16 ---
// Proven ~15 us (HBM/L3-bound). Do not touch.
__global__ __launch_bounds__(256) void transpose_cp(
    const float* __restrict__ in, __half* __restrict__ outT)
{
    int bid = blockIdx.x;               // grid = B * 4 * 625
    int pt   = bid % 625;               // pixel tile (64 pixels)
    int rest = bid / 625;
    int ct   = rest & 3;                // channel tile (64 ch)
    int b    = rest >> 2;

    __shared__ unsigned short tile[64][66];   // [pix][c]
    int tid = threadIdx.x;
    int pix0 = pt * 64, c0 = ct * 64;
    int xl = tid & 63;

    const float* src = in + ((size_t)b * CCH + c0) * FHW + pix0;
    #pragma unroll
    for (int k = 0; k < 16; ++k) {
        int cl = (tid >> 6) + 4 * k;    // 0..63
        tile[xl][cl] = __half_as_ushort(__float2half(src[(size_t)cl * FHW + xl]));
    }
    __syncthreads();

    __half* dst = outT + ((size_t)b * FHW + pix0) * CCH + c0;
    #pragma unroll
    for (int j = 0; j < 8; ++j) {
        int idx = tid + 256 * j;        // 0..2047
        int pl = idx >> 5;              // 0..63
        int cp = idx & 31;              // half2 index: c = 2*cp
        *(unsigned int*)((char*)dst + (size_t)pl * (CCH * 2) + 4 * cp) =
            *(const unsigned int*)&tile[pl][2 * cp];
    }
}

// Async 16B/lane global->LDS. LDS dest = uniform base + lane*16 (HW rule);
// global source address is PER-LANE (may be scattered).
__device__ __forceinline__ void gload16(const void* g, void* s) {
    __builtin_amdgcn_global_load_lds(
        (const __attribute__((address_space(1))) void*)g,
        (__attribute__((address_space(3))) void*)s, 16, 0, 0);
}

// ---------------- ROI Align gather v11: async LDS-staged pipeline -----------
// grid = 4N: block (n = bid>>2, cq = bid&3) owns a 64-ch quarter of ROI n.
// Wave w owns positions p = w, w+4, ..., 48 (13/12 each). Per position:
//   stage: 2 x global_load_lds, each 1 KB = 8 corner-quarters x 128 B
//          (lane: pair q = 8j + (lane>>3), byte (lane&7)*16; LDS linear).
//   pipeline: stage k+2 ahead; counted s_waitcnt vmcnt(4/2/0) (never 0 in
//          steady state) -> load latency hidden without VGPR pressure.
//   consume: lane = one channel; 16 x ds_read_u16 (2 lanes/bank = free) + FMA.
// Output staged in ldso[49][65] (odd stride), coalesced nontemporal writeout.
__global__ __launch_bounds__(256, 4) void roi_gather_v11(
    const __half* __restrict__ featT,  // (B, 40000, 256) fp16
    const float* __restrict__ rois,    // (N, 5)
    float* __restrict__ out,           // (N, 256, 7, 7)
    int N)
{
    int bid = blockIdx.x;
    int n  = bid >> 2;
    int cq = bid & 3;
    int tid  = threadIdx.x;
    int wv   = tid >> 6;                // wave 0..3
    int lane = tid & 63;

    __shared__ __half pix[4][DEPTH][1024];   // 24 KB: per-wave staging ring
    __shared__ float  ldso[NPOS * 65];       // 12.7 KB: output staging

    const float* r = rois + (size_t)n * 5;
    int   b  = (int)r[0];
    float x1 = r[1] * SCALE, y1 = r[2] * SCALE;
    float roi_w = fmaxf(r[3] * SCALE - x1, 1.0f);
    float roi_h = fmaxf(r[4] * SCALE - y1, 1.0f);
    float step_x = roi_w * (1.0f / (OUT_W * RATIO));
    float step_y = roi_h * (1.0f / (OUT_H * RATIO));

    const char* base = (const char*)featT + (size_t)b * ((size_t)FHW * PIXB)
                     + (uint32_t)cq * 128;
    const int qa = lane >> 3;           // lane's pair within each instruction
    const int cc = qa & 3;              // lane's corner
    const uint32_t bq = (uint32_t)(lane & 7) * 16;   // byte within 128B quarter

    const int nk = ((48 - wv) >> 2) + 1;    // 13,12,12,12

    // corner byte-offset for (position p, sample s, corner cc)
    auto corner_off = [&](int p, int s) -> uint32_t {
        int ph = p / OUT_W, pw = p - (p / OUT_W) * OUT_W;
        int iy = s >> 1, ix = s & 1;
        float yy = y1 + ((float)(ph * RATIO + iy) + 0.5f) * step_y;
        float xx = x1 + ((float)(pw * RATIO + ix) + 0.5f) * step_x;
        float yc = fminf(fmaxf(yy, 0.0f), (float)(FH - 1));
        float xc = fminf(fmaxf(xx, 0.0f), (float)(FW - 1));
        int yi0 = (int)yc, xi0 = (int)xc;
        uint32_t rw = (uint32_t)(yi0 * FW + xi0) * PIXB;
        uint32_t dx = (xi0 < FW - 1) ? PIXB : 0u;
        uint32_t dy = (yi0 < FH - 1) ? (FW * PIXB) : 0u;
        return rw + ((cc & 1) ? dx : 0u) + ((cc & 2) ? dy : 0u);
    };

    auto stage = [&](int k) {
        int p = wv + 4 * k;
        uint32_t a0 = corner_off(p, qa >> 2);         // samples 0/1 (j=0)
        uint32_t a1 = corner_off(p, (qa >> 2) + 2);   // samples 2/3 (j=1)
        __half* dst = &pix[wv][k % DEPTH][0];
        gload16(base + a0 + bq, (void*)dst);
        gload16(base + a1 + bq, (void*)(dst + 512));  // +1024 B
    };

    auto consume = [&](int k) {
        int p = wv + 4 * k;
        int ph = p / OUT_W, pw = p - (p / OUT_W) * OUT_W;
        const __half* src = &pix[wv][k % DEPTH][0];
        float acc = 0.0f;
        #pragma unroll
        for (int s = 0; s < 4; ++s) {
            int iy = s >> 1, ix = s & 1;
            float yy = y1 + ((float)(ph * RATIO + iy) + 0.5f) * step_y;
            float xx = x1 + ((float)(pw * RATIO + ix) + 0.5f) * step_x;
            bool  vv = (yy >= -1.0f) && (yy <= (float)FH)
                    && (xx >= -1.0f) && (xx <= (float)FW);
            float yc = fminf(fmaxf(yy, 0.0f), (float)(FH - 1));
            float xc = fminf(fmaxf(xx, 0.0f), (float)(FW - 1));
            float ly = yc - (float)(int)yc, hy = 1.0f - ly;
            float lx = xc - (float)(int)xc, hx = 1.0f - lx;
            float vm = vv ? 0.25f : 0.0f;
            float w0 = hy * hx * vm, w1 = hy * lx * vm;
            float w2 = ly * hx * vm, w3 = ly * lx * vm;
            // pair q = s*4+c at halfs [q*64], lane reads its channel (2B)
            acc = fmaf(__half2float(src[(s * 4 + 0) * 64 + lane]), w0, acc);
            acc = fmaf(__half2float(src[(s * 4 + 1) * 64 + lane]), w1, acc);
            acc = fmaf(__half2float(src[(s * 4 + 2) * 64 + lane]), w2, acc);
            acc = fmaf(__half2float(src[(s * 4 + 3) * 64 + lane]), w3, acc);
        }
        ldso[p * 65 + lane] = acc;    // banks (p+lane)%32: 2/bank = free
    };

    // ---- software pipeline: 2 positions ahead, counted vmcnt ----
    stage(0);
    stage(1);
    #pragma unroll 1
    for (int k = 0; k < nk; ++k) {
        if (k + 2 < nk) {
            stage(k + 2);
            asm volatile("s_waitcnt vmcnt(4)" ::: "memory");  // k's 2 loads done
        } else if (k + 1 < nk) {
            asm volatile("s_waitcnt vmcnt(2)" ::: "memory");
        } else {
            asm volatile("s_waitcnt vmcnt(0)" ::: "memory");
        }
        consume(k);
    }
    __syncthreads();

    // Contiguous 64*49-float region of (N,C,7,7); write-once -> nontemporal.
    float* oblk = out + ((size_t)n * CCH + cq * 64) * NPOS;
    #pragma unroll 1
    for (int o = tid; o < 64 * NPOS; o += 256) {
        int c = o / NPOS;          // magic-mul
        int p = o - c * NPOS;
        __builtin_nontemporal_store(ldso[p * 65 + c], &oblk[o]);
    }
}

// ---------------- Fallback: direct NCHW (round-1 kernel) --------------------
__global__ __launch_bounds__(256) void roi_align_kernel(
    const float* __restrict__ feat, const float* __restrict__ rois,
    float* __restrict__ out, int N, int C, int H, int W)
{
    int idx = blockIdx.x * blockDim.x + threadIdx.x;
    int total = N * C * OUT_H * OUT_W;
    if (idx >= total) return;
    int pw = idx % OUT_W;
    int ph = (idx / OUT_W) % OUT_H;
    int c  = (idx / (OUT_W * OUT_H)) % C;
    int n  = idx / (OUT_W * OUT_H * C);
    const float* r = rois + (size_t)n * 5;
    int   b  = (int)r[0];
    float x1 = r[1] * SCALE, y1 = r[2] * SCALE;
    float roi_w = fmaxf(r[3] * SCALE - x1, 1.0f);
    float roi_h = fmaxf(r[4] * SCALE - y1, 1.0f);
    float step_y = roi_h * (1.0f / (OUT_H * RATIO));
    float step_x = roi_w * (1.0f / (OUT_W * RATIO));
    const float* fptr = feat + ((size_t)b * C + c) * (size_t)(H * W);
    float acc = 0.0f;
    #pragma unroll
    for (int iy = 0; iy < RATIO; ++iy) {
        float y = y1 + ((float)(ph * RATIO + iy) + 0.5f) * step_y;
        bool vy = (y >= -1.0f) && (y <= (float)H);
        float ycl = fminf(fmaxf(y, 0.0f), (float)(H - 1));
        int y0 = (int)floorf(ycl), y1i = min(y0 + 1, H - 1);
        float ly = ycl - (float)y0, hy = 1.0f - ly;
        #pragma unroll
        for (int ix = 0; ix < RATIO; ++ix) {
            float x = x1 + ((float)(pw * RATIO + ix) + 0.5f) * step_x;
            bool vx = (x >= -1.0f) && (x <= (float)W);
            float xcl = fminf(fmaxf(x, 0.0f), (float)(W - 1));
            int x0 = (int)floorf(xcl), x1i = min(x0 + 1, W - 1);
            float lx = xcl - (float)x0, hx = 1.0f - lx;
            const float* row0 = fptr + (size_t)y0 * W;
            const float* row1 = fptr + (size_t)y1i * W;
            float v = hy * hx * row0[x0] + hy * lx * row0[x1i]
                    + ly * hx * row1[x0] + ly * lx * row1[x1i];
            acc += (vy && vx) ? v : 0.0f;
        }
    }
    out[idx] = acc * (1.0f / (RATIO * RATIO));
}

extern "C" void kernel_launch(void* const* d_in, const int* in_sizes, int n_in,
                              void* d_out, int out_size, void* d_ws, size_t ws_size,
                              hipStream_t stream) {
    const float* feat = (const float*)d_in[0];
    const float* rois = (const float*)d_in[1];
    float* out = (float*)d_out;

    const int N = in_sizes[1] / 5;
    const int B = in_sizes[0] / (CCH * FHW);

    size_t need = (size_t)B * FHW * CCH * sizeof(__half);
    if (ws_size >= need) {
        __half* featT = (__half*)d_ws;
        transpose_cp<<<B * 4 * 625, 256, 0, stream>>>(feat, featT);
        roi_gather_v11<<<4 * N, 256, 0, stream>>>(featT, rois, out, N);
    } else {
        int total = N * CCH * OUT_H * OUT_W;
        roi_align_kernel<<<(total + 255) / 256, 256, 0, stream>>>(
            feat, rois, out, N, CCH, FH, FW);
    }
}